// Round 16
// baseline (47.369 us; speedup 1.0000x reference)
//
#include <hip/hip_runtime.h>

// Problem constants (fixed by reference setup_inputs)
#define BB 4
#define LL 4096
#define MM 1024
#define DD 2048
#define SEG 128
#define SM 8            // MM / SEG
#define NSCAN (BB * SEG * 2)
#define BCAST 1024
#define EXIT_EPS 1e-7f

typedef float f32x4 __attribute__((ext_vector_type(4)));

// ---------------------------------------------------------------------------
// Kernel A: per-batch prep (proven R11-R15).
//  - cumsum of boundary_mask; scatter clipped p (stable partition)
//  - row_start[b][t]; Ppref[b][t] (8-wide in-segment prefix products)
// ---------------------------------------------------------------------------
__global__ __launch_bounds__(1024) void prep_kernel(
    const float* __restrict__ bprob,   // (B, L, 2)
    const int*   __restrict__ bmask,   // (B, L)
    float* __restrict__ p_chunked,     // (B, M)
    int*   __restrict__ row_start,     // (B, 1025)
    float* __restrict__ Ppref)         // (B, M)
{
    const int b   = blockIdx.x;
    const int tid = threadIdx.x;
    const int lane = tid & 63;
    const int wid  = tid >> 6;

    __shared__ int wsum[16];
    __shared__ int s_total;
    __shared__ int rs_sh[MM + 1];

    rs_sh[tid] = LL;
    if (tid == 0) rs_sh[MM] = LL;

    int4 mv = reinterpret_cast<const int4*>(bmask + b * LL)[tid];
    int ms[4] = { mv.x, mv.y, mv.z, mv.w };
    int s = ms[0] + ms[1] + ms[2] + ms[3];

    int v = s;
    #pragma unroll
    for (int off = 1; off < 64; off <<= 1) {
        int u = __shfl_up(v, off, 64);
        if (lane >= off) v += u;
    }
    if (lane == 63) wsum[wid] = v;
    __syncthreads();
    if (tid == 0) {
        int acc = 0;
        #pragma unroll
        for (int w = 0; w < 16; ++w) { int t = wsum[w]; wsum[w] = acc; acc += t; }
        s_total = acc;
    }
    __syncthreads();

    const int NB = s_total;
    int e = (v - s) + wsum[wid];

    const int base_l = tid * 4;
    #pragma unroll
    for (int j = 0; j < 4; ++j) {
        int l = base_l + j;
        int m = ms[j];
        int incl = e + m;
        int ci = incl - 1;
        ci = ci < 0 ? 0 : (ci > MM - 1 ? MM - 1 : ci);
        int pci = e - 1;
        pci = pci < 0 ? 0 : (pci > MM - 1 ? MM - 1 : pci);
        if (l == 0 || ci != pci) rs_sh[ci] = l;
        int pos = m ? e : (NB + (l - e));
        if (pos < MM) {
            float2 pv = *reinterpret_cast<const float2*>(
                bprob + ((size_t)b * LL + l) * 2);
            float p = fminf(fmaxf(pv.y, 1e-4f), 1.0f - 1e-4f);
            p_chunked[b * MM + pos] = p;
        }
        e = incl;
    }
    __syncthreads();

    row_start[b * (MM + 1) + tid] = rs_sh[tid];
    if (tid == 0) row_start[b * (MM + 1) + MM] = rs_sh[MM];

    {
        int t = tid;
        float p = p_chunked[b * MM + t];
        float a = (t == 0) ? 0.0f : (1.0f - p);
        float pr = a;
        #pragma unroll
        for (int off = 1; off < SM; off <<= 1) {
            float u = __shfl_up(pr, off, SM);
            if ((t & (SM - 1)) >= off) pr *= u;
        }
        Ppref[b * MM + t] = pr;
    }
}

// ---------------------------------------------------------------------------
// Inline zero-carry scan of segment j (8 rows), d-slice at d0.
// Identical numerics to R15's seglast_kernel.
// ---------------------------------------------------------------------------
static __device__ __forceinline__ f32x4 seg_scan(
    const float* __restrict__ x, const float* __restrict__ sp8,
    int b, int j, int d0)
{
    f32x4 prev = {0.0f, 0.0f, 0.0f, 0.0f};
    const size_t base = ((size_t)b * MM + j * SM) * DD + d0;
    #pragma unroll
    for (int i = 0; i < SM; ++i) {
        float p = sp8[i];
        float ac, bc;
        if (i == 0) { ac = (j == 0) ? 0.0f : (1.0f - p); bc = (j == 0) ? 1.0f : p; }
        else        { ac = 1.0f - p; bc = p; }
        f32x4 xt = *reinterpret_cast<const f32x4*>(x + base + (size_t)i * DD);
        prev = ac * prev + bc * xt;
    }
    return prev;
}

// ---------------------------------------------------------------------------
// Early-exit lookback with INLINE RESCAN: carry-in before segment `seg`.
// c = sum_{j<seg} (prod_{k=j+1..seg-1} Pf_k) * segscan_j, walked backward;
// wave-uniform exit when mult < EXIT_EPS (typ. depth 2-3 for this data).
// ---------------------------------------------------------------------------
static __device__ __forceinline__ f32x4 lookback_rescan(
    const float* __restrict__ x, const float* __restrict__ spc,
    const float* __restrict__ sPf, int b, int seg, int d0)
{
    f32x4 c = {0.0f, 0.0f, 0.0f, 0.0f};
    float mult = 1.0f;
    for (int j = seg - 1; j >= 0; --j) {
        f32x4 sl = seg_scan(x, spc + j * SM, b, j, d0);
        c += mult * sl;
        mult *= sPf[j];
        if (mult < EXIT_EPS) break;       // uniform scalar branch
    }
    return c;
}

// ---------------------------------------------------------------------------
// Fused kernel: direct scatter with inline lookback-rescan. NO seglast pass.
// Blocks [0,NSCAN): rescan predecessors for carry (early exit), scan own 8
//   chunks, write each to its contiguous out-row range (chunk M-1 skipped).
// Blocks [NSCAN,NSCAN+BCAST): lookback over all SEG segments -> y[M-1],
//   stream the clipped tail. No cross-block waits.
// ---------------------------------------------------------------------------
__global__ __launch_bounds__(256) void scatter_kernel(
    const float* __restrict__ x,          // (B, M, D)
    const float* __restrict__ p_chunked,  // (B, M)
    const float* __restrict__ Ppref,      // (B, M)
    const int*   __restrict__ row_start,  // (B, 1025)
    float* __restrict__ out)              // (B, L, D)
{
    const int id  = blockIdx.x;
    const int tid = threadIdx.x;

    __shared__ float sPf[SEG];
    __shared__ float spc[MM];             // all p for this batch (4 KB)

    if (id < NSCAN) {
        const int dsl = id & 1;
        const int seg = (id >> 1) & (SEG - 1);
        const int b   = id >> 8;
        const int d0  = dsl * 1024 + tid * 4;
        const int t0  = seg * SM;

        __shared__ int rs[SM + 1];
        #pragma unroll
        for (int k = tid; k < MM; k += 256) spc[k] = p_chunked[b * MM + k];
        if (tid < SM + 1) rs[tid] = row_start[b * (MM + 1) + t0 + tid];
        if (tid < SEG) sPf[tid] = Ppref[b * MM + tid * SM + SM - 1];
        __syncthreads();

        f32x4 prev = lookback_rescan(x, spc, sPf, b, seg, d0);

        const size_t base = ((size_t)b * MM + t0) * DD + d0;
        #pragma unroll
        for (int i = 0; i < SM; ++i) {
            float p = spc[t0 + i];
            float ac, bc;
            if (i == 0) { ac = (seg == 0) ? 0.0f : (1.0f - p); bc = (seg == 0) ? 1.0f : p; }
            else        { ac = 1.0f - p; bc = p; }
            f32x4 xt = *reinterpret_cast<const f32x4*>(x + base + (size_t)i * DD);
            prev = ac * prev + bc * xt;

            int t = t0 + i;
            if (t == MM - 1) continue;        // tail handled by broadcast blocks
            int l0r = rs[i], l1r = rs[i + 1];
            for (int l = l0r; l < l1r; ++l)
                *reinterpret_cast<f32x4*>(out + ((size_t)b * LL + l) * DD + d0) = prev;
        }
    } else {
        // tail broadcast: rows [row_start[M-1], LL) all equal y[M-1]
        const int j    = id - NSCAN;          // 0..BCAST-1
        const int g    = j & 7;               // (b, dsl)
        const int chnk = j >> 3;              // 0..127
        const int b    = g >> 1;
        const int dsl  = g & 1;
        const int d0   = dsl * 1024 + tid * 4;

        #pragma unroll
        for (int k = tid; k < MM; k += 256) spc[k] = p_chunked[b * MM + k];
        if (tid < SEG) sPf[tid] = Ppref[b * MM + tid * SM + SM - 1];
        __syncthreads();

        // y[M-1] = lookback over ALL segments (seg = SEG in walk terms)
        f32x4 v = lookback_rescan(x, spc, sPf, b, SEG, d0);

        const int l0 = row_start[b * (MM + 1) + (MM - 1)];
        for (int l = l0 + chnk; l < LL; l += 128)
            *reinterpret_cast<f32x4*>(out + ((size_t)b * LL + l) * DD + d0) = v;
    }
}

// ---------------------------------------------------------------------------
extern "C" void kernel_launch(void* const* d_in, const int* in_sizes, int n_in,
                              void* d_out, int out_size, void* d_ws, size_t ws_size,
                              hipStream_t stream) {
    const float* x     = (const float*)d_in[0];
    const float* bprob = (const float*)d_in[1];
    const int*   bmask = (const int*)d_in[2];

    float* out = (float*)d_out;

    // workspace layout (tiny)
    float* p_chunked = (float*)d_ws;                          // B*M
    float* Ppref     = p_chunked + BB * MM;                   // B*M
    int*   row_start = (int*)(Ppref + BB * MM);               // B*1025

    prep_kernel<<<BB, 1024, 0, stream>>>(bprob, bmask, p_chunked, row_start, Ppref);
    scatter_kernel<<<NSCAN + BCAST, 256, 0, stream>>>(
        x, p_chunked, Ppref, row_start, out);
}

// Round 17
// 43.375 us; speedup vs baseline: 1.0921x; 1.0921x over previous
//
#include <hip/hip_runtime.h>

// Problem constants (fixed by reference setup_inputs)
#define BB 4
#define LL 4096
#define MM 1024
#define DD 2048
#define SEG 128
#define SM 8            // MM / SEG
#define NSCAN (BB * SEG * 2)
#define EXIT_EPS 1e-7f

typedef float f32x4 __attribute__((ext_vector_type(4)));

// ---------------------------------------------------------------------------
// Kernel A: per-batch prep (proven R11-R16) + compact Pseg emit.
// ---------------------------------------------------------------------------
__global__ __launch_bounds__(1024) void prep_kernel(
    const float* __restrict__ bprob,   // (B, L, 2)
    const int*   __restrict__ bmask,   // (B, L)
    float* __restrict__ p_chunked,     // (B, M)
    int*   __restrict__ row_start,     // (B, 1025)
    float* __restrict__ Pseg)          // (B, SEG) contiguous segment products
{
    const int b   = blockIdx.x;
    const int tid = threadIdx.x;
    const int lane = tid & 63;
    const int wid  = tid >> 6;

    __shared__ int wsum[16];
    __shared__ int s_total;
    __shared__ int rs_sh[MM + 1];

    rs_sh[tid] = LL;
    if (tid == 0) rs_sh[MM] = LL;

    int4 mv = reinterpret_cast<const int4*>(bmask + b * LL)[tid];
    int ms[4] = { mv.x, mv.y, mv.z, mv.w };
    int s = ms[0] + ms[1] + ms[2] + ms[3];

    int v = s;
    #pragma unroll
    for (int off = 1; off < 64; off <<= 1) {
        int u = __shfl_up(v, off, 64);
        if (lane >= off) v += u;
    }
    if (lane == 63) wsum[wid] = v;
    __syncthreads();
    if (tid == 0) {
        int acc = 0;
        #pragma unroll
        for (int w = 0; w < 16; ++w) { int t = wsum[w]; wsum[w] = acc; acc += t; }
        s_total = acc;
    }
    __syncthreads();

    const int NB = s_total;
    int e = (v - s) + wsum[wid];

    const int base_l = tid * 4;
    #pragma unroll
    for (int j = 0; j < 4; ++j) {
        int l = base_l + j;
        int m = ms[j];
        int incl = e + m;
        int ci = incl - 1;
        ci = ci < 0 ? 0 : (ci > MM - 1 ? MM - 1 : ci);
        int pci = e - 1;
        pci = pci < 0 ? 0 : (pci > MM - 1 ? MM - 1 : pci);
        if (l == 0 || ci != pci) rs_sh[ci] = l;
        int pos = m ? e : (NB + (l - e));
        if (pos < MM) {
            float2 pv = *reinterpret_cast<const float2*>(
                bprob + ((size_t)b * LL + l) * 2);
            float p = fminf(fmaxf(pv.y, 1e-4f), 1.0f - 1e-4f);
            p_chunked[b * MM + pos] = p;
        }
        e = incl;
    }
    __syncthreads();

    row_start[b * (MM + 1) + tid] = rs_sh[tid];
    if (tid == 0) row_start[b * (MM + 1) + MM] = rs_sh[MM];

    // 8-wide in-segment prefix products; segment-end values -> compact Pseg
    {
        int t = tid;
        float p = p_chunked[b * MM + t];
        float a = (t == 0) ? 0.0f : (1.0f - p);
        float pr = a;
        #pragma unroll
        for (int off = 1; off < SM; off <<= 1) {
            float u = __shfl_up(pr, off, SM);
            if ((t & (SM - 1)) >= off) pr *= u;
        }
        if ((t & (SM - 1)) == SM - 1) Pseg[b * SEG + (t >> 3)] = pr;
    }
}

// ---------------------------------------------------------------------------
// Kernel B: per-segment scan emitting ONLY the segment-end value (R15).
// grid = (2, 128, 4) = 1024 blocks, block = 256, f32x4 per thread.
// ---------------------------------------------------------------------------
__global__ __launch_bounds__(256) void seglast_kernel(
    const float* __restrict__ x,          // (B, M, D)
    const float* __restrict__ p_chunked,  // (B, M)
    float* __restrict__ seglast)          // (B, 2, SEG, 1024)
{
    const int tid = threadIdx.x;
    const int dsl = blockIdx.x;
    const int d0  = dsl * 1024 + tid * 4;
    const int seg = blockIdx.y;
    const int b   = blockIdx.z;
    const int t0  = seg * SM;

    __shared__ float sp[SM];
    if (tid < SM) sp[tid] = p_chunked[b * MM + t0 + tid];
    __syncthreads();

    const size_t base = ((size_t)b * MM + t0) * DD + d0;

    f32x4 prev = {0.0f, 0.0f, 0.0f, 0.0f};
    #pragma unroll
    for (int i = 0; i < SM; ++i) {
        float p = sp[i];
        float ac, bc;
        if (i == 0) { ac = (seg == 0) ? 0.0f : (1.0f - p); bc = (seg == 0) ? 1.0f : p; }
        else        { ac = 1.0f - p; bc = p; }
        f32x4 xt = *reinterpret_cast<const f32x4*>(x + base + (size_t)i * DD);
        prev = ac * prev + bc * xt;
    }
    *reinterpret_cast<f32x4*>(
        seglast + (((size_t)(b * 2 + dsl) * SEG + seg)) * 1024 + tid * 4) = prev;
}

// ---------------------------------------------------------------------------
// Early-exit backward lookback on the seglast buffer; Pseg read on demand
// (uniform scalar, L2-hot). Walk from segment `seg` (exclusive) downward.
// ---------------------------------------------------------------------------
static __device__ __forceinline__ f32x4 lookback(
    const float* __restrict__ seglast, const float* __restrict__ Pseg,
    int bd, int b, int seg, int tid)
{
    f32x4 c = {0.0f, 0.0f, 0.0f, 0.0f};
    float mult = 1.0f;
    const float* base = seglast + (size_t)bd * SEG * 1024 + tid * 4;
    for (int j = seg - 1; j >= 0; --j) {
        f32x4 sl = *reinterpret_cast<const f32x4*>(base + (size_t)j * 1024);
        c += mult * sl;
        mult *= Pseg[b * SEG + j];
        if (mult < EXIT_EPS) break;       // uniform scalar branch
    }
    return c;
}

// ---------------------------------------------------------------------------
// Kernel C: direct scatter + merged tail broadcast. grid = NSCAN = 2048.
// Each block: lookback carry -> scan own 8 chunks -> write contiguous out
// ranges (chunk M-1 skipped) -> lookback y[M-1] -> write stride-128 share
// of the clipped tail.
// ---------------------------------------------------------------------------
__global__ __launch_bounds__(256) void scatter_kernel(
    const float* __restrict__ x,          // (B, M, D)
    const float* __restrict__ p_chunked,  // (B, M)
    const float* __restrict__ Pseg,       // (B, SEG)
    const int*   __restrict__ row_start,  // (B, 1025)
    const float* __restrict__ seglast,    // (B, 2, SEG, 1024)
    float* __restrict__ out)              // (B, L, D)
{
    const int id  = blockIdx.x;
    const int tid = threadIdx.x;

    const int dsl = id & 1;
    const int seg = (id >> 1) & (SEG - 1);
    const int b   = id >> 8;
    const int d0  = dsl * 1024 + tid * 4;
    const int t0  = seg * SM;
    const int bd  = b * 2 + dsl;

    __shared__ float sp[SM];
    __shared__ int   rs[SM + 1];
    if (tid < SM) sp[tid] = p_chunked[b * MM + t0 + tid];
    if (tid < SM + 1) rs[tid] = row_start[b * (MM + 1) + t0 + tid];
    __syncthreads();

    // ---- carry-in via early-exit lookback ----
    f32x4 prev = lookback(seglast, Pseg, bd, b, seg, tid);

    // ---- own-segment scan + contiguous-range scatter ----
    const size_t base = ((size_t)b * MM + t0) * DD + d0;
    #pragma unroll
    for (int i = 0; i < SM; ++i) {
        float p = sp[i];
        float ac, bc;
        if (i == 0) { ac = (seg == 0) ? 0.0f : (1.0f - p); bc = (seg == 0) ? 1.0f : p; }
        else        { ac = 1.0f - p; bc = p; }
        f32x4 xt = *reinterpret_cast<const f32x4*>(x + base + (size_t)i * DD);
        prev = ac * prev + bc * xt;

        int t = t0 + i;
        if (t == MM - 1) continue;            // tail written below
        int l0r = rs[i], l1r = rs[i + 1];
        for (int l = l0r; l < l1r; ++l)
            *reinterpret_cast<f32x4*>(out + ((size_t)b * LL + l) * DD + d0) = prev;
    }

    // ---- merged tail: rows [row_start[M-1], LL) all equal y[M-1] ----
    {
        f32x4 v = lookback(seglast, Pseg, bd, b, SEG, tid);
        const int l0 = row_start[b * (MM + 1) + (MM - 1)];
        for (int l = l0 + seg; l < LL; l += SEG)
            *reinterpret_cast<f32x4*>(out + ((size_t)b * LL + l) * DD + d0) = v;
    }
}

// ---------------------------------------------------------------------------
extern "C" void kernel_launch(void* const* d_in, const int* in_sizes, int n_in,
                              void* d_out, int out_size, void* d_ws, size_t ws_size,
                              hipStream_t stream) {
    const float* x     = (const float*)d_in[0];
    const float* bprob = (const float*)d_in[1];
    const int*   bmask = (const int*)d_in[2];

    float* out = (float*)d_out;

    // workspace layout (~4.3 MB)
    float* seglast   = (float*)d_ws;                          // B*2*SEG*1024
    float* p_chunked = seglast + (size_t)BB * 2 * SEG * 1024; // B*M
    float* Pseg      = p_chunked + BB * MM;                   // B*SEG
    int*   row_start = (int*)(Pseg + BB * SEG);               // B*1025

    prep_kernel<<<BB, 1024, 0, stream>>>(bprob, bmask, p_chunked, row_start, Pseg);
    seglast_kernel<<<dim3(2, SEG, BB), 256, 0, stream>>>(x, p_chunked, seglast);
    scatter_kernel<<<NSCAN, 256, 0, stream>>>(
        x, p_chunked, Pseg, row_start, seglast, out);
}